// Round 1
// baseline (10146.214 us; speedup 1.0000x reference)
//
#include <hip/hip_runtime.h>
#include <cstdint>

#define VOCAB 50257
#define EXTRA 64
#define VTOT  50321
#define SEQ   1024
#define TDEC  100
#define UNK   3

// ---------------- workspace layout (float offsets) ----------------
// total bytes needed: 9,817,280 + 96,493,440 = 106,310,720 (~101.4 MiB)
static const size_t OFF_EMB    = 0;        // [1024][128]
static const size_t OFF_WIHT_F = 131072;   // [128][640]
static const size_t OFF_WIHT_B = 212992;   // [128][640]
static const size_t OFF_WTE    = 294912;   // [320][320]  enc_attn_proj^T (k-major)
static const size_t OFF_XG     = 397312;   // [2][1024][640] x-part gates + biases
static const size_t OFF_ENCH   = 1708032;  // [1024][320]
static const size_t OFF_EPH    = 2035712;  // [1024][320] enc_proj_h
static const size_t OFF_DECBUF = 2363392;  // [100][320]
static const size_t OFF_LOGITS = 2395392;  // 50257 (padded to 50272)
static const size_t OFF_SCORES = 2445664;  // 1024
static const size_t OFF_ATTN   = 2446688;  // 1024
static const size_t OFF_CUMA   = 2447712;  // 1024
static const size_t OFF_CUMB   = 2448736;  // 1024
static const size_t OFF_CA     = 2449760;  // 320
static const size_t OFF_CB     = 2450080;  // 320
static const size_t OFF_H      = 2450400;  // 320
static const size_t OFF_HP     = 2450720;  // 320
static const size_t OFF_CONCAT = 2451040;  // 960 = [h | enc_ctx | dec_ctx]
static const size_t OFF_GATES  = 2452000;  // 1280
static const size_t OFF_BM     = 2453280;  // 512 per-block max
static const size_t OFF_BS     = 2453792;  // 512 per-block sumexp
static const size_t OFF_SCAL   = 2454304;  // [0]=p_copy, [1](as int)=tok
static const size_t OFF_WBF16  = 2454320;  // out_proj bf16, 50257*960 ushorts

__device__ __forceinline__ float sigmf(float x) { return 1.f / (1.f + expf(-x)); }

__device__ __forceinline__ float wsum64(float x) {
#pragma unroll
  for (int m = 1; m < 64; m <<= 1) x += __shfl_xor(x, m, 64);
  return x;
}

__device__ __forceinline__ unsigned short bf16r(float x) {
  uint32_t b = __float_as_uint(x);
  uint32_t r = (b + 0x7fffu + ((b >> 16) & 1u)) >> 16;
  return (unsigned short)r;
}

// ---------------- P1: gather embeddings, transposes, zero-init ----------------
__global__ __launch_bounds__(256) void k_setup(float* __restrict__ ws, const int* __restrict__ ids,
                                               const float* __restrict__ embt, const float* __restrict__ ewf,
                                               const float* __restrict__ ewb, const float* __restrict__ eap) {
  int idx = blockIdx.x * 256 + threadIdx.x;
  if (idx < 131072) {
    int tt = idx >> 7, e = idx & 127;
    int id = ids[tt]; if (id >= VOCAB) id = UNK;
    ws[OFF_EMB + idx] = embt[(size_t)id * 128 + e];
  } else if (idx < 212992) {
    int i = idx - 131072;
    int k = i / 640, g = i - (i / 640) * 640;
    ws[OFF_WIHT_F + i] = ewf[(size_t)g * 128 + k];
  } else if (idx < 294912) {
    int i = idx - 212992;
    int k = i / 640, g = i - (i / 640) * 640;
    ws[OFF_WIHT_B + i] = ewb[(size_t)g * 128 + k];
  } else if (idx < 397312) {
    int i = idx - 294912;
    int k = i / 320, j = i - (i / 320) * 320;
    ws[OFF_WTE + i] = eap[(size_t)j * 320 + k];
  } else if (idx < 432000) {
    int i = idx - 397312;
    if (i < 320)        ws[OFF_CA + i] = 0.f;
    else if (i < 640)   ws[OFF_CB + i - 320] = 0.f;
    else if (i < 1664)  ws[OFF_CUMA + i - 640] = 0.f;
    else if (i < 2688)  ws[OFF_CUMB + i - 1664] = 0.f;
    else                ws[OFF_DECBUF + i - 2688] = 0.f;
  } else if (idx == 432000) {
    ws[OFF_SCAL] = 0.f;
  } else if (idx == 432001) {
    ((int*)(ws + OFF_SCAL))[1] = 0;  // START token
  }
}

// ---------------- P2: encoder x-part gates: xg[d][t][g] = emb_row . wihT + biases ----------------
__global__ __launch_bounds__(256) void k_xg(float* __restrict__ ws,
                                            const float* __restrict__ bif, const float* __restrict__ bhf,
                                            const float* __restrict__ bib, const float* __restrict__ bhb) {
  int idx = blockIdx.x * 256 + threadIdx.x;  // < 1310720
  int d = idx / 655360;
  int r = idx - d * 655360;
  int tt = r / 640, g = r - (r / 640) * 640;
  const float* wT = ws + (d ? OFF_WIHT_B : OFF_WIHT_F);
  const float* er = ws + OFF_EMB + (size_t)(d ? (1023 - tt) : tt) * 128;
  float acc = d ? (bib[g] + bhb[g]) : (bif[g] + bhf[g]);
#pragma unroll 4
  for (int k = 0; k < 128; ++k) acc += er[k] * wT[(size_t)k * 640 + g];
  ws[OFF_XG + idx] = acc;
}

// ---------------- P3: out_proj = bf16(tanh(embedding @ vocab_proj)), 64x64 tiles ----------------
__global__ __launch_bounds__(256) void k_outproj(const float* __restrict__ embt, const float* __restrict__ vp,
                                                 float* __restrict__ ws) {
  __shared__ float As[64][128];
  __shared__ float Bs[128][64];
  const int tid = threadIdx.x;
  const int v0 = blockIdx.x * 64, n0 = blockIdx.y * 64;
  for (int c = 0; c < 32; ++c) {
    int idx = c * 256 + tid;
    int m = idx >> 7, k = idx & 127;
    int v = v0 + m;
    As[m][k] = (v < VOCAB) ? embt[(size_t)v * 128 + k] : 0.f;
    int k2 = idx >> 6, n = idx & 63;
    Bs[k2][n] = vp[(size_t)k2 * 960 + n0 + n];
  }
  __syncthreads();
  const int mi = tid >> 4, ni = tid & 15;
  float acc[4][4] = {};
  for (int k = 0; k < 128; ++k) {
    float a0 = As[mi * 4 + 0][k], a1 = As[mi * 4 + 1][k], a2 = As[mi * 4 + 2][k], a3 = As[mi * 4 + 3][k];
    float4 b = *(const float4*)&Bs[k][ni * 4];
    acc[0][0] += a0 * b.x; acc[0][1] += a0 * b.y; acc[0][2] += a0 * b.z; acc[0][3] += a0 * b.w;
    acc[1][0] += a1 * b.x; acc[1][1] += a1 * b.y; acc[1][2] += a1 * b.z; acc[1][3] += a1 * b.w;
    acc[2][0] += a2 * b.x; acc[2][1] += a2 * b.y; acc[2][2] += a2 * b.z; acc[2][3] += a2 * b.w;
    acc[3][0] += a3 * b.x; acc[3][1] += a3 * b.y; acc[3][2] += a3 * b.z; acc[3][3] += a3 * b.w;
  }
  unsigned short* W = (unsigned short*)(ws + OFF_WBF16);
#pragma unroll
  for (int i = 0; i < 4; ++i) {
    int v = v0 + mi * 4 + i;
    if (v < VOCAB) {
      ushort4 pk;
      pk.x = bf16r(tanhf(acc[i][0]));
      pk.y = bf16r(tanhf(acc[i][1]));
      pk.z = bf16r(tanhf(acc[i][2]));
      pk.w = bf16r(tanhf(acc[i][3]));
      *(ushort4*)&W[(size_t)v * 960 + n0 + ni * 4] = pk;
    }
  }
}

// ---------------- P4: sequential bi-LSTM encoder; whh in registers (5 rows x 40 k / thread) ----------------
__global__ __launch_bounds__(512) void k_encoder(float* __restrict__ ws, const float* __restrict__ whh_f,
                                                 const float* __restrict__ whh_b) {
  const int dir = blockIdx.x;
  const int tid = threadIdx.x;
  const float* whh = dir ? whh_b : whh_f;
  const float* xg = ws + OFF_XG + (size_t)dir * 655360;
  __shared__ float hbuf[160];
  __shared__ float part[4][640];
  const int q = tid & 127, kg = tid >> 7, ks = kg * 40;
  float w[5][40];
#pragma unroll
  for (int j = 0; j < 5; ++j)
#pragma unroll
    for (int i = 0; i < 40; ++i)
      w[j][i] = whh[(size_t)(5 * q + j) * 160 + ks + i];
  float cst = 0.f;
  if (tid < 160) hbuf[tid] = 0.f;
  __syncthreads();
  for (int t = 0; t < 1024; ++t) {
    float acc[5] = {0.f, 0.f, 0.f, 0.f, 0.f};
#pragma unroll
    for (int i4 = 0; i4 < 10; ++i4) {
      float4 h4 = *(const float4*)&hbuf[ks + i4 * 4];
#pragma unroll
      for (int j = 0; j < 5; ++j)
        acc[j] += w[j][i4 * 4 + 0] * h4.x + w[j][i4 * 4 + 1] * h4.y + w[j][i4 * 4 + 2] * h4.z + w[j][i4 * 4 + 3] * h4.w;
    }
#pragma unroll
    for (int j = 0; j < 5; ++j) part[kg][5 * q + j] = acc[j];
    __syncthreads();
    if (tid < 160) {
      const int u = tid;
      float gi = xg[(size_t)t * 640 + u];
      float gf = xg[(size_t)t * 640 + 160 + u];
      float gg = xg[(size_t)t * 640 + 320 + u];
      float go = xg[(size_t)t * 640 + 480 + u];
#pragma unroll
      for (int k2 = 0; k2 < 4; ++k2) {
        gi += part[k2][u]; gf += part[k2][160 + u]; gg += part[k2][320 + u]; go += part[k2][480 + u];
      }
      cst = sigmf(gf) * cst + sigmf(gi) * tanhf(gg);
      float hn = sigmf(go) * tanhf(cst);
      hbuf[u] = hn;
      int trow = dir ? (1023 - t) : t;
      ws[OFF_ENCH + (size_t)trow * 320 + dir * 160 + u] = hn;
    }
    __syncthreads();
  }
  if (tid < 160) ws[OFF_H + dir * 160 + tid] = hbuf[tid];  // h0 = [hfin_f, hfin_b]
}

// ---------------- P5: enc_proj_h = enc_h @ enc_attn_proj^T ----------------
__global__ __launch_bounds__(256) void k_encproj(float* __restrict__ ws) {
  int idx = blockIdx.x * 256 + threadIdx.x;  // < 327680
  int s = idx / 320, j = idx - (idx / 320) * 320;
  const float* er = ws + OFF_ENCH + (size_t)s * 320;
  const float* wt = ws + OFF_WTE;
  float acc = 0.f;
#pragma unroll 4
  for (int k = 0; k < 320; ++k) acc += er[k] * wt[(size_t)k * 320 + j];
  ws[OFF_EPH + idx] = acc;
}

// ---------------- KA: decoder gates = dec_wih@x + dec_whh@h + biases (wave per row) ----------------
__global__ __launch_bounds__(256) void k_gates(float* __restrict__ ws, const float* __restrict__ embt,
                                               const float* __restrict__ dwih, const float* __restrict__ dwhh,
                                               const float* __restrict__ dbih, const float* __restrict__ dbhh) {
  const int tid = threadIdx.x, bid = blockIdx.x;
  if (bid == 0) {
    for (int i = tid; i < 640; i += 256) {
      if (i < 320) ws[OFF_HP + i] = 0.f;
      else         ws[OFF_CONCAT + i] = 0.f;  // zero enc_ctx slot [320,640)
    }
  }
  int tok = ((const int*)(ws + OFF_SCAL))[1];
  int tokm = (tok >= VOCAB) ? UNK : tok;
  const int l = tid & 63, wv = tid >> 6;
  float xv[2], hv[5];
#pragma unroll
  for (int c = 0; c < 2; ++c) xv[c] = embt[(size_t)tokm * 128 + c * 64 + l];
#pragma unroll
  for (int c = 0; c < 5; ++c) hv[c] = ws[OFF_H + c * 64 + l];
  const int wg = bid * 4 + wv;
  for (int i = 0; i < 16; ++i) {
    const int r = wg * 16 + i;
    float acc = 0.f;
#pragma unroll
    for (int c = 0; c < 2; ++c) acc += dwih[(size_t)r * 128 + c * 64 + l] * xv[c];
#pragma unroll
    for (int c = 0; c < 5; ++c) acc += dwhh[(size_t)r * 320 + c * 64 + l] * hv[c];
    acc = wsum64(acc);
    if (l == 0) ws[OFF_GATES + r] = acc + dbih[r] + dbhh[r];
  }
}

// ---------------- KC: h,c update (redundant per block) + scores + hp partials ----------------
__global__ __launch_bounds__(512) void k_hstep(float* __restrict__ ws, const float* __restrict__ dap, int t) {
  __shared__ float hL[320];
  const int tid = threadIdx.x, bid = blockIdx.x;
  const int par = t & 1;
  const float* cin = ws + (par ? OFF_CB : OFF_CA);
  float* cout = ws + (par ? OFF_CA : OFF_CB);
  if (tid < 320) {
    float gi = ws[OFF_GATES + tid];
    float gf = ws[OFF_GATES + 320 + tid];
    float gg = ws[OFF_GATES + 640 + tid];
    float go = ws[OFF_GATES + 960 + tid];
    float c = sigmf(gf) * cin[tid] + sigmf(gi) * tanhf(gg);
    float hn = sigmf(go) * tanhf(c);
    hL[tid] = hn;
    if (bid == 0) {
      cout[tid] = c;
      ws[OFF_H + tid] = hn;
      ws[OFF_CONCAT + tid] = hn;
      ws[OFF_DECBUF + (size_t)t * 320 + tid] = hn;
    }
  }
  __syncthreads();
  if (bid < 32) {
    const int l = tid & 63, wv = tid >> 6;
    float hv[5];
#pragma unroll
    for (int c = 0; c < 5; ++c) hv[c] = hL[c * 64 + l];
#pragma unroll
    for (int i = 0; i < 4; ++i) {
      int s = bid * 32 + wv * 4 + i;
      const float* er = ws + OFF_EPH + (size_t)s * 320;
      float acc = 0.f;
#pragma unroll
      for (int c = 0; c < 5; ++c) acc += er[c * 64 + l] * hv[c];
      acc = wsum64(acc);
      if (l == 0) ws[OFF_SCORES + s] = acc;
    }
  } else {
    const int q = bid - 32;  // 0..7, i-range of 40
    if (tid < 320) {
      float acc = 0.f;
#pragma unroll 8
      for (int ii = 0; ii < 40; ++ii) {
        int i = q * 40 + ii;
        acc += hL[i] * dap[(size_t)i * 320 + tid];
      }
      atomicAdd(&ws[OFF_HP + tid], acc);
    }
  }
}

// ---------------- KE: temporal-attn softmax + enc_ctx (blocks 0..15) ; cum, dec-attn, dec_ctx (block 16) ----------------
__global__ __launch_bounds__(512) void k_attn(float* __restrict__ ws, int t) {
  const int tid = threadIdx.x, bid = blockIdx.x;
  const int par = t & 1;
  const float* cumin = ws + (par ? OFF_CUMB : OFF_CUMA);
  float* cumout = ws + (par ? OFF_CUMA : OFF_CUMB);

  __shared__ float tvL[1024];
  __shared__ float red[512];
  __shared__ float attnL[64];
  __shared__ float dsL[128];
  __shared__ float daL[128];

  if (bid < 16) {
    float s0 = ws[OFF_SCORES + tid];
    float s1 = ws[OFF_SCORES + tid + 512];
    float t0 = (t == 0) ? s0 : expf(s0) / cumin[tid];
    float t1 = (t == 0) ? s1 : expf(s1) / cumin[tid + 512];
    tvL[tid] = t0; tvL[tid + 512] = t1;
    red[tid] = fmaxf(t0, t1);
    __syncthreads();
    for (int off = 256; off > 0; off >>= 1) { if (tid < off) red[tid] = fmaxf(red[tid], red[tid + off]); __syncthreads(); }
    float mx = red[0];
    __syncthreads();
    red[tid] = expf(t0 - mx) + expf(t1 - mx);
    __syncthreads();
    for (int off = 256; off > 0; off >>= 1) { if (tid < off) red[tid] += red[tid + off]; __syncthreads(); }
    float S = red[0];
    __syncthreads();
    if (tid < 64) {
      int s = bid * 64 + tid;
      float a = expf(tvL[s] - mx) / S;
      attnL[tid] = a;
      ws[OFF_ATTN + s] = a;
    }
    __syncthreads();
    if (tid < 320) {
      float acc = 0.f;
      const float* eh = ws + OFF_ENCH + (size_t)(bid * 64) * 320 + tid;
#pragma unroll 4
      for (int k2 = 0; k2 < 64; ++k2) acc += attnL[k2] * eh[(size_t)k2 * 320];
      atomicAdd(&ws[OFF_CONCAT + 320 + tid], acc);
    }
  } else {
    // block 16: cum update + intra-decoder attention
    cumout[tid] = cumin[tid] + ws[OFF_SCORES + tid];
    cumout[tid + 512] = cumin[tid + 512] + ws[OFF_SCORES + tid + 512];
    const int l = tid & 63, wv = tid >> 6;
    float hpv[5];
#pragma unroll
    for (int c = 0; c < 5; ++c) hpv[c] = ws[OFF_HP + c * 64 + l];
    if (tid < 28) dsL[100 + tid] = -1e9f;
#pragma unroll
    for (int k2 = 0; k2 < 13; ++k2) {
      int tp = wv + 8 * k2;
      if (tp < 100) {
        float acc = 0.f;
#pragma unroll
        for (int c = 0; c < 5; ++c) acc += hpv[c] * ws[OFF_DECBUF + (size_t)tp * 320 + c * 64 + l];
        acc = wsum64(acc);
        if (l == 0) dsL[tp] = acc;
      }
    }
    __syncthreads();
    float v = -1e9f;
    if (tid < 128) { v = (tid < t) ? dsL[tid] : -1e9f; red[tid] = v; }
    __syncthreads();
    for (int off = 64; off > 0; off >>= 1) { if (tid < off) red[tid] = fmaxf(red[tid], red[tid + off]); __syncthreads(); }
    float mx = red[0];
    __syncthreads();
    float e = (tid < 128) ? expf(v - mx) : 0.f;
    if (tid < 128) red[tid] = e;
    __syncthreads();
    for (int off = 64; off > 0; off >>= 1) { if (tid < off) red[tid] += red[tid + off]; __syncthreads(); }
    float S = red[0];
    __syncthreads();
    if (tid < 128) daL[tid] = e / S;
    __syncthreads();
    if (tid < 320) {
      float acc = 0.f;
      for (int tp = 0; tp < t; ++tp) acc += daL[tp] * ws[OFF_DECBUF + (size_t)tp * 320 + tid];
      ws[OFF_CONCAT + 640 + tid] = acc;  // t==0 -> 0
    }
  }
}

// ---------------- KF: logits = out_proj(bf16) @ concat + bias ; per-block online (max,sumexp); p_copy ----------------
__global__ __launch_bounds__(256) void k_logits(float* __restrict__ ws, const float* __restrict__ ob,
                                                const float* __restrict__ sw, const float* __restrict__ sb) {
  const int tid = threadIdx.x, bid = blockIdx.x;
  const int l = tid & 63, wv = tid >> 6;
  const uint32_t* W = (const uint32_t*)(ws + OFF_WBF16);
  float2 cf[8];
  const float2* c2 = (const float2*)(ws + OFF_CONCAT);
#pragma unroll
  for (int c = 0; c < 8; ++c) cf[c] = c2[c * 64 + l];
  if (bid == 0 && tid < 64) {
    float acc = 0.f;
#pragma unroll
    for (int c = 0; c < 15; ++c) acc += sw[c * 64 + l] * ws[OFF_CONCAT + c * 64 + l];
    acc = wsum64(acc);
    if (l == 0) ws[OFF_SCAL] = 1.f / (1.f + expf(-(acc + sb[0])));
  }
  float m = -1e30f, s = 0.f;
  for (int v = bid * 4 + wv; v < VOCAB; v += 2048) {
    const uint32_t* row = W + (size_t)v * 480;
    float acc = 0.f;
#pragma unroll
    for (int c = 0; c < 8; ++c) {
      uint32_t u = row[c * 64 + l];
      acc += __uint_as_float(u << 16) * cf[c].x + __uint_as_float(u & 0xffff0000u) * cf[c].y;
    }
    acc = wsum64(acc);
    float logit = acc + ob[v];
    if (l == 0) ws[OFF_LOGITS + v] = logit;
    float m2 = fmaxf(m, logit);
    s = s * expf(m - m2) + expf(logit - m2);
    m = m2;
  }
  __shared__ float rm[256], rs[256];
  rm[tid] = m; rs[tid] = s;
  __syncthreads();
  for (int off = 128; off > 0; off >>= 1) {
    if (tid < off) {
      float m1 = rm[tid], m2 = rm[tid + off];
      float mm = fmaxf(m1, m2);
      rs[tid] = rs[tid] * expf(m1 - mm) + rs[tid + off] * expf(m2 - mm);
      rm[tid] = mm;
    }
    __syncthreads();
  }
  if (tid == 0) { ws[OFF_BM + bid] = rm[0]; ws[OFF_BS + bid] = rs[0]; }
}

// ---------------- KH: final gen distribution write ----------------
__global__ __launch_bounds__(512) void k_final(float* __restrict__ ws, float* __restrict__ out, int t) {
  __shared__ float rm[512], rs[512];
  const int tid = threadIdx.x, bid = blockIdx.x;
  rm[tid] = ws[OFF_BM + tid];
  rs[tid] = ws[OFF_BS + tid];
  __syncthreads();
  for (int off = 256; off > 0; off >>= 1) {
    if (tid < off) {
      float m1 = rm[tid], m2 = rm[tid + off];
      float mm = fmaxf(m1, m2);
      rs[tid] = rs[tid] * expf(m1 - mm) + rs[tid + off] * expf(m2 - mm);
      rm[tid] = mm;
    }
    __syncthreads();
  }
  float M = rm[0], S = rs[0];
  float scale = (1.f - ws[OFF_SCAL]) / S;
  int v = bid * 512 + tid;
  if (v < VTOT)
    out[(size_t)t * VTOT + v] = (v < VOCAB) ? scale * expf(ws[OFF_LOGITS + v] - M) : 0.f;
}

// ---------------- KI: pointer scatter-add + greedy argmax -> next token ----------------
__global__ __launch_bounds__(1024) void k_scatter(float* __restrict__ ws, const int* __restrict__ ids,
                                                  float* __restrict__ out, int t) {
  const int tid = threadIdx.x;
  float* row = out + (size_t)t * VTOT;
  float pc = ws[OFF_SCAL];
  atomicAdd(&row[ids[tid]], pc * ws[OFF_ATTN + tid]);
  __threadfence();
  __syncthreads();
  float bv = -1.f; int bi = 0;
  for (int v = tid; v < VTOT; v += 1024) {
    float x = row[v];
    if (x > bv) { bv = x; bi = v; }
  }
  __shared__ float svv[1024];
  __shared__ int sii[1024];
  svv[tid] = bv; sii[tid] = bi;
  __syncthreads();
  for (int off = 512; off > 0; off >>= 1) {
    if (tid < off) {
      float ov = svv[tid + off]; int oi = sii[tid + off];
      if (ov > svv[tid] || (ov == svv[tid] && oi < sii[tid])) { svv[tid] = ov; sii[tid] = oi; }
    }
    __syncthreads();
  }
  if (tid == 0) ((int*)(ws + OFF_SCAL))[1] = sii[0];
}

// ---------------- host ----------------
extern "C" void kernel_launch(void* const* d_in, const int* in_sizes, int n_in,
                              void* d_out, int out_size, void* d_ws, size_t ws_size,
                              hipStream_t stream) {
  const int*   ids  = (const int*)d_in[0];
  const float* embt = (const float*)d_in[1];
  const float* ewf  = (const float*)d_in[2];
  const float* ehf  = (const float*)d_in[3];
  const float* ebif = (const float*)d_in[4];
  const float* ebhf = (const float*)d_in[5];
  const float* ewb  = (const float*)d_in[6];
  const float* ehb  = (const float*)d_in[7];
  const float* ebib = (const float*)d_in[8];
  const float* ebhb = (const float*)d_in[9];
  const float* dwih = (const float*)d_in[10];
  const float* dwhh = (const float*)d_in[11];
  const float* dbih = (const float*)d_in[12];
  const float* dbhh = (const float*)d_in[13];
  // d_in[14] = enc_attn_proj (transposed in k_setup)
  const float* eap  = (const float*)d_in[14];
  const float* dap  = (const float*)d_in[15];
  const float* vp   = (const float*)d_in[16];
  const float* ob   = (const float*)d_in[17];
  const float* sw   = (const float*)d_in[18];
  const float* sb   = (const float*)d_in[19];
  float* out = (float*)d_out;
  float* ws  = (float*)d_ws;

  k_setup<<<1688, 256, 0, stream>>>(ws, ids, embt, ewf, ewb, eap);
  k_xg<<<5120, 256, 0, stream>>>(ws, ebif, ebhf, ebib, ebhb);
  k_outproj<<<dim3(786, 15), 256, 0, stream>>>(embt, vp, ws);
  k_encoder<<<2, 512, 0, stream>>>(ws, ehf, ehb);
  k_encproj<<<1280, 256, 0, stream>>>(ws);

  for (int t = 0; t < TDEC; ++t) {
    k_gates<<<20, 256, 0, stream>>>(ws, embt, dwih, dwhh, dbih, dbhh);
    k_hstep<<<40, 512, 0, stream>>>(ws, dap, t);
    k_attn<<<17, 512, 0, stream>>>(ws, t);
    k_logits<<<512, 256, 0, stream>>>(ws, ob, sw, sb);
    k_final<<<99, 512, 0, stream>>>(ws, out, t);
    k_scatter<<<1, 1024, 0, stream>>>(ws, ids, out, t);
  }
}